// Round 6
// baseline (119.677 us; speedup 1.0000x reference)
//
#include <hip/hip_runtime.h>
#include <math.h>

#define MD 128
#define NA 2048
#define AS 512
#define NS 32768
#define NBE 512
#define W1 1792
#define W2 2304
#define PI 3.14159265358979323846
#define KTH ((float)(PI / 98304.0))

__device__ __forceinline__ float lrelu(float v) { return v > 0.f ? v : 0.2f * v; }

// ---------------------------------------------------------------------------
// P1: hidden layers for all 3 stacks. Grid (128 row-groups, 3 stacks) x 128.
// ---------------------------------------------------------------------------
__global__ __launch_bounds__(128) void hidden_kernel(
    const float* __restrict__ x, const float* __restrict__ times,
    const float* __restrict__ tw0, const float* __restrict__ tb0,
    const float* __restrict__ tw1, const float* __restrict__ tb1,
    const float* __restrict__ tw2, const float* __restrict__ tb2,
    const float* __restrict__ sw0, const float* __restrict__ sb0,
    const float* __restrict__ sw1, const float* __restrict__ sb1,
    const float* __restrict__ aw0, const float* __restrict__ ab0,
    const float* __restrict__ aw1, const float* __restrict__ ab1,
    const float* __restrict__ aw2, const float* __restrict__ ab2,
    float* __restrict__ timev, float* __restrict__ ampv,
    float* __restrict__ h2sel)
{
  const int rg = blockIdx.x;      // 0..127 (4 rows each)
  const int stack = blockIdx.y;   // 0=time 1=amp 2=sel
  const int tid = threadIdx.x;

  __shared__ float xs[4][MD];
  __shared__ double dA[4][MD], dB[4][MD];
  __shared__ float fA[4][MD], fB[4][MD];

#pragma unroll
  for (int j = 0; j < 4; ++j) xs[j][tid] = x[(rg * 4 + j) * MD + tid];
  __syncthreads();

  if (stack == 0) {
    // ---- time stack, fp64 (dNc = 32767*dtime: precision-critical) ----
    {
      double b = (double)tb0[tid];
      double s[4] = {b, b, b, b};
#pragma unroll 8
      for (int k = 0; k < MD; ++k) {
        double w = (double)tw0[k * MD + tid];
#pragma unroll
        for (int j = 0; j < 4; ++j) s[j] += (double)xs[j][k] * w;
      }
#pragma unroll
      for (int j = 0; j < 4; ++j) dA[j][tid] = s[j] > 0.0 ? s[j] : 0.2 * s[j];
      __syncthreads();
    }
    {
      double b = (double)tb1[tid];
      double s[4] = {b, b, b, b};
#pragma unroll 8
      for (int k = 0; k < MD; ++k) {
        double w = (double)tw1[k * MD + tid];
#pragma unroll
        for (int j = 0; j < 4; ++j) s[j] += dA[j][k] * w;
      }
#pragma unroll
      for (int j = 0; j < 4; ++j) dB[j][tid] = s[j] > 0.0 ? s[j] : 0.2 * s[j];
      __syncthreads();
    }
    {
      double w2 = (double)tw2[tid];
#pragma unroll
      for (int j = 0; j < 4; ++j) dA[j][tid] = dB[j][tid] * w2;
      __syncthreads();
      for (int off = 64; off > 0; off >>= 1) {
        if (tid < off) {
#pragma unroll
          for (int j = 0; j < 4; ++j) dA[j][tid] += dA[j][tid + off];
        }
        __syncthreads();
      }
      if (tid == 0) {
#pragma unroll
        for (int j = 0; j < 4; ++j) {
          double tval = dA[j][0] + (double)tb2[0];
          double sg = 1.0 / (1.0 + exp(-tval));
          float tf = (float)sg;            // round like the fp32 reference
          timev[rg * 4 + j] = tf * 1.0f + times[rg * 4 + j];
        }
      }
    }
  } else if (stack == 1) {
    // ---- amp stack, fp32 ----
    {
      float b = ab0[tid];
      float s[4] = {b, b, b, b};
#pragma unroll 8
      for (int k = 0; k < MD; ++k) {
        float w = aw0[k * MD + tid];
#pragma unroll
        for (int j = 0; j < 4; ++j) s[j] += xs[j][k] * w;
      }
#pragma unroll
      for (int j = 0; j < 4; ++j) fA[j][tid] = lrelu(s[j]);
      __syncthreads();
    }
    {
      float b = ab1[tid];
      float s[4] = {b, b, b, b};
#pragma unroll 8
      for (int k = 0; k < MD; ++k) {
        float w = aw1[k * MD + tid];
#pragma unroll
        for (int j = 0; j < 4; ++j) s[j] += fA[j][k] * w;
      }
#pragma unroll
      for (int j = 0; j < 4; ++j) fB[j][tid] = lrelu(s[j]);
      __syncthreads();
    }
    {
      float w2 = aw2[tid];
#pragma unroll
      for (int j = 0; j < 4; ++j) fA[j][tid] = fB[j][tid] * w2;
      __syncthreads();
      for (int off = 64; off > 0; off >>= 1) {
        if (tid < off) {
#pragma unroll
          for (int j = 0; j < 4; ++j) fA[j][tid] += fA[j][tid + off];
        }
        __syncthreads();
      }
      if (tid == 0) {
#pragma unroll
        for (int j = 0; j < 4; ++j) {
          float av = fA[j][0] + ab2[0];
          ampv[rg * 4 + j] = av * av;
        }
      }
    }
  } else {
    // ---- selection hidden, fp32 ----
    {
      float b = sb0[tid];
      float s[4] = {b, b, b, b};
#pragma unroll 8
      for (int k = 0; k < MD; ++k) {
        float w = sw0[k * MD + tid];
#pragma unroll
        for (int j = 0; j < 4; ++j) s[j] += xs[j][k] * w;
      }
#pragma unroll
      for (int j = 0; j < 4; ++j) fA[j][tid] = lrelu(s[j]);
      __syncthreads();
    }
    {
      float b = sb1[tid];
      float s[4] = {b, b, b, b};
#pragma unroll 8
      for (int k = 0; k < MD; ++k) {
        float w = sw1[k * MD + tid];
#pragma unroll
        for (int j = 0; j < 4; ++j) s[j] += fA[j][k] * w;
      }
#pragma unroll
      for (int j = 0; j < 4; ++j)
        h2sel[(rg * 4 + j) * MD + tid] = lrelu(s[j]);
    }
  }
}

// ---------------------------------------------------------------------------
// P2: selection logits + gumbel + per-tile argmax partials.
// Grid (16 o-tiles, 128 be-groups) x 128.
// ---------------------------------------------------------------------------
__global__ __launch_bounds__(128) void logits_kernel(
    const float* __restrict__ h2sel, const float* __restrict__ gu,
    const float* __restrict__ sw2, const float* __restrict__ sb2,
    float2* __restrict__ partials)
{
  const int ot = blockIdx.x;     // 0..15
  const int beg = blockIdx.y;    // 0..127
  const int tid = threadIdx.x;
  const int o = ot * 128 + tid;
  const int wave = tid >> 6, lane = tid & 63;

  __shared__ float h2s[4][MD];
  __shared__ float wv[2][4];
  __shared__ int wi[2][4];

#pragma unroll
  for (int j = 0; j < 4; ++j) h2s[j][tid] = h2sel[(beg * 4 + j) * MD + tid];
  __syncthreads();

  float b = sb2[o];
  float acc[4] = {b, b, b, b};
#pragma unroll 16
  for (int k = 0; k < MD; ++k) {
    float w = sw2[k * NA + o];
#pragma unroll
    for (int j = 0; j < 4; ++j) acc[j] = fmaf(h2s[j][k], w, acc[j]);
  }

#pragma unroll
  for (int j = 0; j < 4; ++j) {
    float u = gu[(beg * 4 + j) * NA + o];
    float g = -logf(-logf(u + 1e-10f) + 1e-10f);
    float v = acc[j] + g;
    int idx = o;
    for (int off = 32; off > 0; off >>= 1) {
      float ov = __shfl_xor(v, off);
      int oi = __shfl_xor(idx, off);
      if (ov > v || (ov == v && oi < idx)) { v = ov; idx = oi; }
    }
    if (lane == 0) { wv[wave][j] = v; wi[wave][j] = idx; }
  }
  __syncthreads();
  if (tid == 0) {
#pragma unroll
    for (int j = 0; j < 4; ++j) {
      float v0 = wv[0][j], v1 = wv[1][j];
      int i0 = wi[0][j], i1 = wi[1][j];
      bool take1 = (v1 > v0) || (v1 == v0 && i1 < i0);
      float bv = take1 ? v1 : v0;
      int bi = take1 ? i1 : i0;
      partials[(beg * 4 + j) * 16 + ot] = make_float2(bv, __int_as_float(bi));
    }
  }
}

// ---------------------------------------------------------------------------
// P3: final argmax + atom norm + shift params + G/moments/params. Grid 512.
// ---------------------------------------------------------------------------
__global__ __launch_bounds__(128) void finalize_kernel(
    const float2* __restrict__ partials, const float* __restrict__ timev,
    const float* __restrict__ ampv, const float* __restrict__ atoms,
    float* __restrict__ G, int* __restrict__ m0s, float* __restrict__ fracs,
    float4* __restrict__ params)
{
  const int be = blockIdx.x;
  const int tid = threadIdx.x;
  __shared__ float red[128];
  __shared__ float m_red[128][8];
  __shared__ float sc_coef, sc_inv;
  __shared__ int sc_idx;

  if (tid < 64) {
    float v = -3.4e38f;
    int idx = 0x7fffffff;
    if (tid < 16) {
      float2 p = partials[be * 16 + tid];
      v = p.x;
      idx = __float_as_int(p.y);
    }
    for (int off = 8; off > 0; off >>= 1) {
      float ov = __shfl_xor(v, off);
      int oi = __shfl_xor(idx, off);
      if (ov > v || (ov == v && oi < idx)) { v = ov; idx = oi; }
    }
    if (tid == 0) sc_idx = idx;
  }
  __syncthreads();
  const int idx = sc_idx;

  {
    float ss = 0.f;
    for (int i = tid; i < AS; i += 128) { float v = atoms[idx * AS + i]; ss += v * v; }
    red[tid] = ss;
    __syncthreads();
    for (int off = 64; off > 0; off >>= 1) {
      if (tid < off) red[tid] += red[tid + off];
      __syncthreads();
    }
    if (tid == 0) {
      sc_inv = 1.f / (sqrtf(red[0]) + 1e-8f);
      double Nc = (double)timev[be] * (1610612736.0 / 49153.0);
      double rr = rint(Nc);
      int m0 = (int)rr;
      float fr = (float)(Nc - rr);
      if (fabsf(fr) < 1e-9f) fr = (fr < 0.f) ? -1e-9f : 1e-9f;
      m0s[be] = m0;
      fracs[be] = fr;
      sc_coef = ampv[be] * ((m0 & 1) ? 1.0f : -1.0f) *
                sinf((float)PI * fr) * (1.0f / 98304.0f);
      red[64] = (float)m0;
      red[65] = fr;
    }
    __syncthreads();
  }

  const float cf = sc_coef * sc_inv;
  float mk[7] = {0.f, 0.f, 0.f, 0.f, 0.f, 0.f, 0.f};
  for (int t = tid; t < AS; t += 128) {
    float av = atoms[idx * AS + t] * cf;
    float gv = (t & 1) ? -av : av;
    G[be * AS + t] = gv;
    float q = (255.5f - (float)t) * KTH;
    float pw = gv;
    mk[0] += pw;
#pragma unroll
    for (int k = 1; k < 7; ++k) { pw *= q; mk[k] += pw; }
  }
#pragma unroll
  for (int k = 0; k < 7; ++k) m_red[tid][k] = mk[k];
  __syncthreads();
  for (int off = 64; off > 0; off >>= 1) {
    if (tid < off) {
#pragma unroll
      for (int k = 0; k < 7; ++k) m_red[tid][k] += m_red[tid + off][k];
    }
    __syncthreads();
  }
  if (tid == 0) {
    int m0 = (int)red[64];
    float fr = red[65];
    float uc = (float)((double)m0 + (double)fr + 255.5);
    params[be * 3 + 0] = make_float4(uc, (float)(m0 - W1), (float)(m0 + W2), m_red[0][0]);
    params[be * 3 + 1] = make_float4(m_red[0][1], m_red[0][2], m_red[0][3], m_red[0][4]);
    params[be * 3 + 2] = make_float4(m_red[0][5], m_red[0][6], 0.f, 0.f);
  }
}

// ---------------------------------------------------------------------------
// Far field: per (b,t), P=6 Taylor of cot around each e's tap center.
// ---------------------------------------------------------------------------
__global__ __launch_bounds__(256) void far_kernel(
    const float4* __restrict__ params, float* __restrict__ out)
{
  const int b = blockIdx.y;
  const int t = blockIdx.x * 256 + threadIdx.x;
  __shared__ float4 Pl[192];
  if (threadIdx.x < 192) Pl[threadIdx.x] = params[b * 192 + threadIdx.x];
  __syncthreads();

  const float tf = (float)t;
  float acc = 0.f;
#pragma unroll 2
  for (int e = 0; e < 64; ++e) {
    const float4 A = Pl[e * 3 + 0];
    const float4 B = Pl[e * 3 + 1];
    const float4 C = Pl[e * 3 + 2];
    float u  = tf - A.x;
    float th = u * KTH;
    float sn = __sinf(th);
    float cs = __cosf(th);
    float c  = cs * __builtin_amdgcn_rcpf(sn);
    float u2  = __builtin_fmaf(c, c, 1.f);
    float c2  = c + c;
    float u22 = u2 + u2;
    float a2  = c * u2;
    float a3  = (-1.f / 3.f) * __builtin_fmaf(c2, a2, u2 * u2);
    float a4  = 0.5f * __builtin_fmaf(-c, a3, u2 * a2);
    float s5  = __builtin_fmaf(c2, a4, a2 * a2);
    s5        = __builtin_fmaf(-u22, a3, s5);
    float a5  = -0.2f * s5;
    float s6  = __builtin_fmaf(c, a5, a2 * a3);
    s6        = __builtin_fmaf(-u2, a4, s6);
    float a6  = (-1.f / 3.f) * s6;
    float y = c * A.w;
    y = __builtin_fmaf(-u2, B.x, y);
    y = __builtin_fmaf(a2, B.y, y);
    y = __builtin_fmaf(a3, B.z, y);
    y = __builtin_fmaf(a4, B.w, y);
    y = __builtin_fmaf(a5, C.x, y);
    y = __builtin_fmaf(a6, C.y, y);
    bool farq = (tf < A.y) || (tf >= A.z);
    acc += farq ? y : 0.f;
  }
  out[b * NS + t] = (t & 1) ? -acc : acc;
}

// ---------------------------------------------------------------------------
// Near field: one block per (chunk, be), 512 threads, RT=4.
// Thread tid owns outputs start+4*tid..+3. Sliding 2xfloat4 register window;
// per k-step ONE new float4 at group (tid+k+1): lane-contiguous 16B stride ->
// canonical conflict-free b128 pattern (reads AND table-build writes).
// G float4 read per k is wave-uniform (broadcast, free). No swizzle anywhere.
// ---------------------------------------------------------------------------
__global__ __launch_bounds__(512) void near_kernel(
    const float* __restrict__ G, const int* __restrict__ m0s,
    const float* __restrict__ fracs, float* __restrict__ out)
{
  const int chunk = blockIdx.x;   // 0..1
  const int be    = blockIdx.y;   // 0..511
  const int tid   = threadIdx.x;  // 0..511
  const int m0 = m0s[be];
  const int start = m0 - W1 + chunk * 2048;
  if (start >= NS) return;        // block-uniform: window past output range
  const float fr = fracs[be];
  const int b = be >> 6;

  __shared__ float4 Tl4[640];     // logical v = start-511 .. start+2047
  __shared__ float4 Gl4[128];
  float* Tl = (float*)Tl4;
  float* Gl = (float*)Gl4;

  Gl[tid] = (tid < AS) ? G[be * AS + tid] : 0.f;
  for (int i = tid; i < 2559; i += 512) {
    int v = start - 511 + i;
    float w = (float)(v - m0) - fr;           // never 0 (|fr| >= 1e-9)
    float th = w * KTH;                       // |th| <= 0.074
    float q = th * th;
    float sn = th * __builtin_fmaf(q, __builtin_fmaf(q, (1.f / 120.f), (-1.f / 6.f)), 1.f);
    float cs = __builtin_fmaf(q, __builtin_fmaf(q, (1.f / 24.f), -0.5f), 1.f);
    Tl[i] = cs * __builtin_amdgcn_rcpf(sn);
  }
  __syncthreads();

  float acc0 = 0.f, acc1 = 0.f, acc2 = 0.f, acc3 = 0.f;
  float4 q0 = Tl4[tid];
#pragma unroll 8
  for (int k = 0; k < 128; ++k) {
    float4 q1 = Tl4[tid + k + 1];
    const float4 gq = Gl4[127 - k];           // G[tc..tc+3], tc = 508-4k (broadcast)
    // f[j] = window value at offset j; out[r] += G[tc+d] * f[3 + r - d]
    // d=0 -> gq.x pairs f[3+r]; d=1 -> gq.y f[2+r]; d=2 -> gq.z f[1+r]; d=3 -> gq.w f[r]
    acc0 = fmaf(gq.w, q0.x, acc0);
    acc1 = fmaf(gq.w, q0.y, acc1);
    acc2 = fmaf(gq.w, q0.z, acc2);
    acc3 = fmaf(gq.w, q0.w, acc3);
    acc0 = fmaf(gq.z, q0.y, acc0);
    acc1 = fmaf(gq.z, q0.z, acc1);
    acc2 = fmaf(gq.z, q0.w, acc2);
    acc3 = fmaf(gq.z, q1.x, acc3);
    acc0 = fmaf(gq.y, q0.z, acc0);
    acc1 = fmaf(gq.y, q0.w, acc1);
    acc2 = fmaf(gq.y, q1.x, acc2);
    acc3 = fmaf(gq.y, q1.y, acc3);
    acc0 = fmaf(gq.x, q0.w, acc0);
    acc1 = fmaf(gq.x, q1.x, acc1);
    acc2 = fmaf(gq.x, q1.y, acc2);
    acc3 = fmaf(gq.x, q1.z, acc3);
    q0 = q1;
  }

  const int tb = start + tid * 4;
  float accs[4] = {acc0, acc1, acc2, acc3};
#pragma unroll
  for (int r = 0; r < 4; ++r) {
    int t = tb + r;
    if (t >= 0 && t < NS) {
      float v = (t & 1) ? -accs[r] : accs[r];
      atomicAdd(&out[b * NS + t], v);
    }
  }
}

// ---------------------------------------------------------------------------
extern "C" void kernel_launch(void* const* d_in, const int* in_sizes, int n_in,
                              void* d_out, int out_size, void* d_ws, size_t ws_size,
                              hipStream_t stream) {
  const float* x     = (const float*)d_in[0];
  const float* times = (const float*)d_in[1];
  const float* gu    = (const float*)d_in[2];
  const float* atoms = (const float*)d_in[3];
  const float* tw0 = (const float*)d_in[4];  const float* tb0 = (const float*)d_in[5];
  const float* tw1 = (const float*)d_in[6];  const float* tb1 = (const float*)d_in[7];
  const float* tw2 = (const float*)d_in[8];  const float* tb2 = (const float*)d_in[9];
  const float* sw0 = (const float*)d_in[10]; const float* sb0 = (const float*)d_in[11];
  const float* sw1 = (const float*)d_in[12]; const float* sb1 = (const float*)d_in[13];
  const float* sw2 = (const float*)d_in[14]; const float* sb2 = (const float*)d_in[15];
  const float* aw0 = (const float*)d_in[16]; const float* ab0 = (const float*)d_in[17];
  const float* aw1 = (const float*)d_in[18]; const float* ab1 = (const float*)d_in[19];
  const float* aw2 = (const float*)d_in[20]; const float* ab2 = (const float*)d_in[21];

  // ws layout (bytes):
  //   G 0..1MB | m0s 1048576 | fracs 1050624 | params 1052672 | timev 1077248
  //   ampv 1079296 | h2sel 1081344 (256KB) | partials 1343488 (64KB)
  char* wsb = (char*)d_ws;
  float*  G        = (float*)wsb;
  int*    m0s      = (int*)(wsb + 1048576);
  float*  fracs    = (float*)(wsb + 1050624);
  float4* params   = (float4*)(wsb + 1052672);
  float*  timev    = (float*)(wsb + 1077248);
  float*  ampv     = (float*)(wsb + 1079296);
  float*  h2sel    = (float*)(wsb + 1081344);
  float2* partials = (float2*)(wsb + 1343488);

  hidden_kernel<<<dim3(NBE / 4, 3), 128, 0, stream>>>(
      x, times, tw0, tb0, tw1, tb1, tw2, tb2,
      sw0, sb0, sw1, sb1, aw0, ab0, aw1, ab1, aw2, ab2,
      timev, ampv, h2sel);

  logits_kernel<<<dim3(16, NBE / 4), 128, 0, stream>>>(h2sel, gu, sw2, sb2, partials);

  finalize_kernel<<<NBE, 128, 0, stream>>>(partials, timev, ampv, atoms,
                                           G, m0s, fracs, params);

  far_kernel<<<dim3(NS / 256, 8), 256, 0, stream>>>(params, (float*)d_out);

  near_kernel<<<dim3(2, NBE), 512, 0, stream>>>(G, m0s, fracs, (float*)d_out);
}

// Round 7
// 95.177 us; speedup vs baseline: 1.2574x; 1.2574x over previous
//
#include <hip/hip_runtime.h>
#include <math.h>

#define MD 128
#define NA 2048
#define AS 512
#define NS 32768
#define NBE 512
#define W1 1792
#define W2 2304
#define PI 3.14159265358979323846
#define KTH ((float)(PI / 98304.0))

__device__ __forceinline__ float lrelu(float v) { return v > 0.f ? v : 0.2f * v; }

// ---------------------------------------------------------------------------
// P1: hidden layers for all 3 stacks. Grid (128 row-groups, 3 stacks) x 128.
// ---------------------------------------------------------------------------
__global__ __launch_bounds__(128) void hidden_kernel(
    const float* __restrict__ x, const float* __restrict__ times,
    const float* __restrict__ tw0, const float* __restrict__ tb0,
    const float* __restrict__ tw1, const float* __restrict__ tb1,
    const float* __restrict__ tw2, const float* __restrict__ tb2,
    const float* __restrict__ sw0, const float* __restrict__ sb0,
    const float* __restrict__ sw1, const float* __restrict__ sb1,
    const float* __restrict__ aw0, const float* __restrict__ ab0,
    const float* __restrict__ aw1, const float* __restrict__ ab1,
    const float* __restrict__ aw2, const float* __restrict__ ab2,
    float* __restrict__ timev, float* __restrict__ ampv,
    float* __restrict__ h2sel)
{
  const int rg = blockIdx.x;      // 0..127 (4 rows each)
  const int stack = blockIdx.y;   // 0=time 1=amp 2=sel
  const int tid = threadIdx.x;

  __shared__ float xs[4][MD];
  __shared__ double dA[4][MD], dB[4][MD];
  __shared__ float fA[4][MD], fB[4][MD];

#pragma unroll
  for (int j = 0; j < 4; ++j) xs[j][tid] = x[(rg * 4 + j) * MD + tid];
  __syncthreads();

  if (stack == 0) {
    // ---- time stack, fp64 (dNc = 32767*dtime: precision-critical) ----
    {
      double b = (double)tb0[tid];
      double s[4] = {b, b, b, b};
#pragma unroll 8
      for (int k = 0; k < MD; ++k) {
        double w = (double)tw0[k * MD + tid];
#pragma unroll
        for (int j = 0; j < 4; ++j) s[j] += (double)xs[j][k] * w;
      }
#pragma unroll
      for (int j = 0; j < 4; ++j) dA[j][tid] = s[j] > 0.0 ? s[j] : 0.2 * s[j];
      __syncthreads();
    }
    {
      double b = (double)tb1[tid];
      double s[4] = {b, b, b, b};
#pragma unroll 8
      for (int k = 0; k < MD; ++k) {
        double w = (double)tw1[k * MD + tid];
#pragma unroll
        for (int j = 0; j < 4; ++j) s[j] += dA[j][k] * w;
      }
#pragma unroll
      for (int j = 0; j < 4; ++j) dB[j][tid] = s[j] > 0.0 ? s[j] : 0.2 * s[j];
      __syncthreads();
    }
    {
      double w2 = (double)tw2[tid];
#pragma unroll
      for (int j = 0; j < 4; ++j) dA[j][tid] = dB[j][tid] * w2;
      __syncthreads();
      for (int off = 64; off > 0; off >>= 1) {
        if (tid < off) {
#pragma unroll
          for (int j = 0; j < 4; ++j) dA[j][tid] += dA[j][tid + off];
        }
        __syncthreads();
      }
      if (tid == 0) {
#pragma unroll
        for (int j = 0; j < 4; ++j) {
          double tval = dA[j][0] + (double)tb2[0];
          double sg = 1.0 / (1.0 + exp(-tval));
          float tf = (float)sg;            // round like the fp32 reference
          timev[rg * 4 + j] = tf * 1.0f + times[rg * 4 + j];
        }
      }
    }
  } else if (stack == 1) {
    // ---- amp stack, fp32 ----
    {
      float b = ab0[tid];
      float s[4] = {b, b, b, b};
#pragma unroll 8
      for (int k = 0; k < MD; ++k) {
        float w = aw0[k * MD + tid];
#pragma unroll
        for (int j = 0; j < 4; ++j) s[j] += xs[j][k] * w;
      }
#pragma unroll
      for (int j = 0; j < 4; ++j) fA[j][tid] = lrelu(s[j]);
      __syncthreads();
    }
    {
      float b = ab1[tid];
      float s[4] = {b, b, b, b};
#pragma unroll 8
      for (int k = 0; k < MD; ++k) {
        float w = aw1[k * MD + tid];
#pragma unroll
        for (int j = 0; j < 4; ++j) s[j] += fA[j][k] * w;
      }
#pragma unroll
      for (int j = 0; j < 4; ++j) fB[j][tid] = lrelu(s[j]);
      __syncthreads();
    }
    {
      float w2 = aw2[tid];
#pragma unroll
      for (int j = 0; j < 4; ++j) fA[j][tid] = fB[j][tid] * w2;
      __syncthreads();
      for (int off = 64; off > 0; off >>= 1) {
        if (tid < off) {
#pragma unroll
          for (int j = 0; j < 4; ++j) fA[j][tid] += fA[j][tid + off];
        }
        __syncthreads();
      }
      if (tid == 0) {
#pragma unroll
        for (int j = 0; j < 4; ++j) {
          float av = fA[j][0] + ab2[0];
          ampv[rg * 4 + j] = av * av;
        }
      }
    }
  } else {
    // ---- selection hidden, fp32 ----
    {
      float b = sb0[tid];
      float s[4] = {b, b, b, b};
#pragma unroll 8
      for (int k = 0; k < MD; ++k) {
        float w = sw0[k * MD + tid];
#pragma unroll
        for (int j = 0; j < 4; ++j) s[j] += xs[j][k] * w;
      }
#pragma unroll
      for (int j = 0; j < 4; ++j) fA[j][tid] = lrelu(s[j]);
      __syncthreads();
    }
    {
      float b = sb1[tid];
      float s[4] = {b, b, b, b};
#pragma unroll 8
      for (int k = 0; k < MD; ++k) {
        float w = sw1[k * MD + tid];
#pragma unroll
        for (int j = 0; j < 4; ++j) s[j] += fA[j][k] * w;
      }
#pragma unroll
      for (int j = 0; j < 4; ++j)
        h2sel[(rg * 4 + j) * MD + tid] = lrelu(s[j]);
    }
  }
}

// ---------------------------------------------------------------------------
// P2: selection logits + gumbel + per-tile argmax partials.
// Grid (16 o-tiles, 128 be-groups) x 128.
// ---------------------------------------------------------------------------
__global__ __launch_bounds__(128) void logits_kernel(
    const float* __restrict__ h2sel, const float* __restrict__ gu,
    const float* __restrict__ sw2, const float* __restrict__ sb2,
    float2* __restrict__ partials)
{
  const int ot = blockIdx.x;     // 0..15
  const int beg = blockIdx.y;    // 0..127
  const int tid = threadIdx.x;
  const int o = ot * 128 + tid;
  const int wave = tid >> 6, lane = tid & 63;

  __shared__ float h2s[4][MD];
  __shared__ float wv[2][4];
  __shared__ int wi[2][4];

#pragma unroll
  for (int j = 0; j < 4; ++j) h2s[j][tid] = h2sel[(beg * 4 + j) * MD + tid];
  __syncthreads();

  float b = sb2[o];
  float acc[4] = {b, b, b, b};
#pragma unroll 16
  for (int k = 0; k < MD; ++k) {
    float w = sw2[k * NA + o];
#pragma unroll
    for (int j = 0; j < 4; ++j) acc[j] = fmaf(h2s[j][k], w, acc[j]);
  }

#pragma unroll
  for (int j = 0; j < 4; ++j) {
    float u = gu[(beg * 4 + j) * NA + o];
    float g = -logf(-logf(u + 1e-10f) + 1e-10f);
    float v = acc[j] + g;
    int idx = o;
    for (int off = 32; off > 0; off >>= 1) {
      float ov = __shfl_xor(v, off);
      int oi = __shfl_xor(idx, off);
      if (ov > v || (ov == v && oi < idx)) { v = ov; idx = oi; }
    }
    if (lane == 0) { wv[wave][j] = v; wi[wave][j] = idx; }
  }
  __syncthreads();
  if (tid == 0) {
#pragma unroll
    for (int j = 0; j < 4; ++j) {
      float v0 = wv[0][j], v1 = wv[1][j];
      int i0 = wi[0][j], i1 = wi[1][j];
      bool take1 = (v1 > v0) || (v1 == v0 && i1 < i0);
      float bv = take1 ? v1 : v0;
      int bi = take1 ? i1 : i0;
      partials[(beg * 4 + j) * 16 + ot] = make_float2(bv, __int_as_float(bi));
    }
  }
}

// ---------------------------------------------------------------------------
// P3: final argmax + atom norm + shift params + G/moments/params. Grid 512.
// ---------------------------------------------------------------------------
__global__ __launch_bounds__(128) void finalize_kernel(
    const float2* __restrict__ partials, const float* __restrict__ timev,
    const float* __restrict__ ampv, const float* __restrict__ atoms,
    float* __restrict__ G, int* __restrict__ m0s, float* __restrict__ fracs,
    float4* __restrict__ params)
{
  const int be = blockIdx.x;
  const int tid = threadIdx.x;
  __shared__ float red[128];
  __shared__ float m_red[128][8];
  __shared__ float sc_coef, sc_inv;
  __shared__ int sc_idx;

  if (tid < 64) {
    float v = -3.4e38f;
    int idx = 0x7fffffff;
    if (tid < 16) {
      float2 p = partials[be * 16 + tid];
      v = p.x;
      idx = __float_as_int(p.y);
    }
    for (int off = 8; off > 0; off >>= 1) {
      float ov = __shfl_xor(v, off);
      int oi = __shfl_xor(idx, off);
      if (ov > v || (ov == v && oi < idx)) { v = ov; idx = oi; }
    }
    if (tid == 0) sc_idx = idx;
  }
  __syncthreads();
  const int idx = sc_idx;

  {
    float ss = 0.f;
    for (int i = tid; i < AS; i += 128) { float v = atoms[idx * AS + i]; ss += v * v; }
    red[tid] = ss;
    __syncthreads();
    for (int off = 64; off > 0; off >>= 1) {
      if (tid < off) red[tid] += red[tid + off];
      __syncthreads();
    }
    if (tid == 0) {
      sc_inv = 1.f / (sqrtf(red[0]) + 1e-8f);
      double Nc = (double)timev[be] * (1610612736.0 / 49153.0);
      double rr = rint(Nc);
      int m0 = (int)rr;
      float fr = (float)(Nc - rr);
      if (fabsf(fr) < 1e-9f) fr = (fr < 0.f) ? -1e-9f : 1e-9f;
      m0s[be] = m0;
      fracs[be] = fr;
      sc_coef = ampv[be] * ((m0 & 1) ? 1.0f : -1.0f) *
                sinf((float)PI * fr) * (1.0f / 98304.0f);
      red[64] = (float)m0;
      red[65] = fr;
    }
    __syncthreads();
  }

  const float cf = sc_coef * sc_inv;
  float mk[7] = {0.f, 0.f, 0.f, 0.f, 0.f, 0.f, 0.f};
  for (int t = tid; t < AS; t += 128) {
    float av = atoms[idx * AS + t] * cf;
    float gv = (t & 1) ? -av : av;
    G[be * AS + t] = gv;
    float q = (255.5f - (float)t) * KTH;
    float pw = gv;
    mk[0] += pw;
#pragma unroll
    for (int k = 1; k < 7; ++k) { pw *= q; mk[k] += pw; }
  }
#pragma unroll
  for (int k = 0; k < 7; ++k) m_red[tid][k] = mk[k];
  __syncthreads();
  for (int off = 64; off > 0; off >>= 1) {
    if (tid < off) {
#pragma unroll
      for (int k = 0; k < 7; ++k) m_red[tid][k] += m_red[tid + off][k];
    }
    __syncthreads();
  }
  if (tid == 0) {
    int m0 = (int)red[64];
    float fr = red[65];
    float uc = (float)((double)m0 + (double)fr + 255.5);
    params[be * 3 + 0] = make_float4(uc, (float)(m0 - W1), (float)(m0 + W2), m_red[0][0]);
    params[be * 3 + 1] = make_float4(m_red[0][1], m_red[0][2], m_red[0][3], m_red[0][4]);
    params[be * 3 + 2] = make_float4(m_red[0][5], m_red[0][6], 0.f, 0.f);
  }
}

// ---------------------------------------------------------------------------
// Far field: per (b,t), P=6 Taylor of cot around each e's tap center.
// ---------------------------------------------------------------------------
__global__ __launch_bounds__(256) void far_kernel(
    const float4* __restrict__ params, float* __restrict__ out)
{
  const int b = blockIdx.y;
  const int t = blockIdx.x * 256 + threadIdx.x;
  __shared__ float4 Pl[192];
  if (threadIdx.x < 192) Pl[threadIdx.x] = params[b * 192 + threadIdx.x];
  __syncthreads();

  const float tf = (float)t;
  float acc = 0.f;
#pragma unroll 2
  for (int e = 0; e < 64; ++e) {
    const float4 A = Pl[e * 3 + 0];
    const float4 B = Pl[e * 3 + 1];
    const float4 C = Pl[e * 3 + 2];
    float u  = tf - A.x;
    float th = u * KTH;
    float sn = __sinf(th);
    float cs = __cosf(th);
    float c  = cs * __builtin_amdgcn_rcpf(sn);
    float u2  = __builtin_fmaf(c, c, 1.f);
    float c2  = c + c;
    float u22 = u2 + u2;
    float a2  = c * u2;
    float a3  = (-1.f / 3.f) * __builtin_fmaf(c2, a2, u2 * u2);
    float a4  = 0.5f * __builtin_fmaf(-c, a3, u2 * a2);
    float s5  = __builtin_fmaf(c2, a4, a2 * a2);
    s5        = __builtin_fmaf(-u22, a3, s5);
    float a5  = -0.2f * s5;
    float s6  = __builtin_fmaf(c, a5, a2 * a3);
    s6        = __builtin_fmaf(-u2, a4, s6);
    float a6  = (-1.f / 3.f) * s6;
    float y = c * A.w;
    y = __builtin_fmaf(-u2, B.x, y);
    y = __builtin_fmaf(a2, B.y, y);
    y = __builtin_fmaf(a3, B.z, y);
    y = __builtin_fmaf(a4, B.w, y);
    y = __builtin_fmaf(a5, C.x, y);
    y = __builtin_fmaf(a6, C.y, y);
    bool farq = (tf < A.y) || (tf >= A.z);
    acc += farq ? y : 0.f;
  }
  out[b * NS + t] = (t & 1) ? -acc : acc;
}

// ---------------------------------------------------------------------------
// Near field: one block per (chunk, be), 256 threads, RT=8.
// Split-table layout: Tsplit[0..319] = even float4 groups, [320..639] = odd.
// Thread tid needs window groups {2(tid+k+1), 2(tid+k+1)+1} per k-step ->
// Tsplit[tid+k+1] and Tsplit[320+tid+k+1]: BOTH lane-contiguous b128 reads
// (canonical conflict-free), 2 reads per 64 FMA (RT=8 traffic ratio).
// Build writes are 2-way bank-aliased (free, m136). G read is broadcast.
// ---------------------------------------------------------------------------
__global__ __launch_bounds__(256) void near_kernel(
    const float* __restrict__ G, const int* __restrict__ m0s,
    const float* __restrict__ fracs, float* __restrict__ out)
{
  const int chunk = blockIdx.x;   // 0..1
  const int be    = blockIdx.y;   // 0..511
  const int tid   = threadIdx.x;  // 0..255
  const int m0 = m0s[be];
  const int start = m0 - W1 + chunk * 2048;
  if (start >= NS) return;        // block-uniform: window past output range
  const float fr = fracs[be];
  const int b = be >> 6;

  __shared__ float4 Tsplit[640];  // [0..319]=even groups, [320..639]=odd groups
  __shared__ float4 Gl4[128];
  float* Tf = (float*)Tsplit;
  float* Gl = (float*)Gl4;

  for (int i = tid; i < AS; i += 256) Gl[i] = G[be * AS + i];
  for (int i = tid; i < 2560; i += 256) {
    int v = start - 511 + i;
    float w = (float)(v - m0) - fr;           // never 0 (|fr| >= 1e-9)
    float th = w * KTH;                       // |th| <= 0.074
    float q = th * th;
    float sn = th * __builtin_fmaf(q, __builtin_fmaf(q, (1.f / 120.f), (-1.f / 6.f)), 1.f);
    float cs = __builtin_fmaf(q, __builtin_fmaf(q, (1.f / 24.f), -0.5f), 1.f);
    float val = cs * __builtin_amdgcn_rcpf(sn);
    int g = i >> 2;                           // logical float4 group
    int s = (g >> 1) * 4 + (i & 3) + (g & 1) * 1280;  // split index (floats)
    Tf[s] = val;
  }
  __syncthreads();

  float acc[8];
#pragma unroll
  for (int r = 0; r < 8; ++r) acc[r] = 0.f;

  float Wf[16];
  {
    float4 qa = Tsplit[tid];         // groups 2*tid   -> Wf[0..3]
    float4 qb = Tsplit[320 + tid];   // group 2*tid+1  -> Wf[4..7]
    Wf[0] = qa.x; Wf[1] = qa.y; Wf[2] = qa.z; Wf[3] = qa.w;
    Wf[4] = qb.x; Wf[5] = qb.y; Wf[6] = qb.z; Wf[7] = qb.w;
  }
#pragma unroll 4
  for (int k = 0; k < 64; ++k) {
    float4 qa = Tsplit[tid + k + 1];         // group 2(tid+k+1)
    float4 qb = Tsplit[320 + tid + k + 1];   // group 2(tid+k+1)+1
    Wf[8]  = qa.x; Wf[9]  = qa.y; Wf[10] = qa.z; Wf[11] = qa.w;
    Wf[12] = qb.x; Wf[13] = qb.y; Wf[14] = qb.z; Wf[15] = qb.w;
    const int tc = 504 - 8 * k;
    const float4 gq0 = Gl4[tc >> 2];
    const float4 gq1 = Gl4[(tc >> 2) + 1];
    const float gvals[8] = {gq0.x, gq0.y, gq0.z, gq0.w,
                            gq1.x, gq1.y, gq1.z, gq1.w};
#pragma unroll
    for (int d = 0; d < 8; ++d) {
      const float gv = gvals[d];
#pragma unroll
      for (int r = 0; r < 8; ++r)
        acc[r] = fmaf(gv, Wf[7 + r - d], acc[r]);
    }
#pragma unroll
    for (int m = 0; m < 8; ++m) Wf[m] = Wf[m + 8];
  }

  const int tb = start + tid * 8;
#pragma unroll
  for (int r = 0; r < 8; ++r) {
    int t = tb + r;
    if (t >= 0 && t < NS) {
      float v = (t & 1) ? -acc[r] : acc[r];
      atomicAdd(&out[b * NS + t], v);
    }
  }
}

// ---------------------------------------------------------------------------
extern "C" void kernel_launch(void* const* d_in, const int* in_sizes, int n_in,
                              void* d_out, int out_size, void* d_ws, size_t ws_size,
                              hipStream_t stream) {
  const float* x     = (const float*)d_in[0];
  const float* times = (const float*)d_in[1];
  const float* gu    = (const float*)d_in[2];
  const float* atoms = (const float*)d_in[3];
  const float* tw0 = (const float*)d_in[4];  const float* tb0 = (const float*)d_in[5];
  const float* tw1 = (const float*)d_in[6];  const float* tb1 = (const float*)d_in[7];
  const float* tw2 = (const float*)d_in[8];  const float* tb2 = (const float*)d_in[9];
  const float* sw0 = (const float*)d_in[10]; const float* sb0 = (const float*)d_in[11];
  const float* sw1 = (const float*)d_in[12]; const float* sb1 = (const float*)d_in[13];
  const float* sw2 = (const float*)d_in[14]; const float* sb2 = (const float*)d_in[15];
  const float* aw0 = (const float*)d_in[16]; const float* ab0 = (const float*)d_in[17];
  const float* aw1 = (const float*)d_in[18]; const float* ab1 = (const float*)d_in[19];
  const float* aw2 = (const float*)d_in[20]; const float* ab2 = (const float*)d_in[21];

  // ws layout (bytes):
  //   G 0..1MB | m0s 1048576 | fracs 1050624 | params 1052672 | timev 1077248
  //   ampv 1079296 | h2sel 1081344 (256KB) | partials 1343488 (64KB)
  char* wsb = (char*)d_ws;
  float*  G        = (float*)wsb;
  int*    m0s      = (int*)(wsb + 1048576);
  float*  fracs    = (float*)(wsb + 1050624);
  float4* params   = (float4*)(wsb + 1052672);
  float*  timev    = (float*)(wsb + 1077248);
  float*  ampv     = (float*)(wsb + 1079296);
  float*  h2sel    = (float*)(wsb + 1081344);
  float2* partials = (float2*)(wsb + 1343488);

  hidden_kernel<<<dim3(NBE / 4, 3), 128, 0, stream>>>(
      x, times, tw0, tb0, tw1, tb1, tw2, tb2,
      sw0, sb0, sw1, sb1, aw0, ab0, aw1, ab1, aw2, ab2,
      timev, ampv, h2sel);

  logits_kernel<<<dim3(16, NBE / 4), 128, 0, stream>>>(h2sel, gu, sw2, sb2, partials);

  finalize_kernel<<<NBE, 128, 0, stream>>>(partials, timev, ampv, atoms,
                                           G, m0s, fracs, params);

  far_kernel<<<dim3(NS / 256, 8), 256, 0, stream>>>(params, (float*)d_out);

  near_kernel<<<dim3(2, NBE), 256, 0, stream>>>(G, m0s, fracs, (float*)d_out);
}

// Round 8
// 90.018 us; speedup vs baseline: 1.3295x; 1.0573x over previous
//
#include <hip/hip_runtime.h>
#include <math.h>

#define MD 128
#define NA 2048
#define AS 512
#define NS 32768
#define NBE 512
#define W1 768
#define W2 1280
#define PI 3.14159265358979323846
#define KTH ((float)(PI / 98304.0))

__device__ __forceinline__ float lrelu(float v) { return v > 0.f ? v : 0.2f * v; }

// ---------------------------------------------------------------------------
// P1: hidden layers for all 3 stacks. Grid (128 row-groups, 3 stacks) x 128.
// ---------------------------------------------------------------------------
__global__ __launch_bounds__(128) void hidden_kernel(
    const float* __restrict__ x, const float* __restrict__ times,
    const float* __restrict__ tw0, const float* __restrict__ tb0,
    const float* __restrict__ tw1, const float* __restrict__ tb1,
    const float* __restrict__ tw2, const float* __restrict__ tb2,
    const float* __restrict__ sw0, const float* __restrict__ sb0,
    const float* __restrict__ sw1, const float* __restrict__ sb1,
    const float* __restrict__ aw0, const float* __restrict__ ab0,
    const float* __restrict__ aw1, const float* __restrict__ ab1,
    const float* __restrict__ aw2, const float* __restrict__ ab2,
    float* __restrict__ timev, float* __restrict__ ampv,
    float* __restrict__ h2sel)
{
  const int rg = blockIdx.x;      // 0..127 (4 rows each)
  const int stack = blockIdx.y;   // 0=time 1=amp 2=sel
  const int tid = threadIdx.x;

  __shared__ float xs[4][MD];
  __shared__ double dA[4][MD], dB[4][MD];
  __shared__ float fA[4][MD], fB[4][MD];

#pragma unroll
  for (int j = 0; j < 4; ++j) xs[j][tid] = x[(rg * 4 + j) * MD + tid];
  __syncthreads();

  if (stack == 0) {
    // ---- time stack, fp64 (dNc = 32767*dtime: precision-critical) ----
    {
      double b = (double)tb0[tid];
      double s[4] = {b, b, b, b};
#pragma unroll 8
      for (int k = 0; k < MD; ++k) {
        double w = (double)tw0[k * MD + tid];
#pragma unroll
        for (int j = 0; j < 4; ++j) s[j] += (double)xs[j][k] * w;
      }
#pragma unroll
      for (int j = 0; j < 4; ++j) dA[j][tid] = s[j] > 0.0 ? s[j] : 0.2 * s[j];
      __syncthreads();
    }
    {
      double b = (double)tb1[tid];
      double s[4] = {b, b, b, b};
#pragma unroll 8
      for (int k = 0; k < MD; ++k) {
        double w = (double)tw1[k * MD + tid];
#pragma unroll
        for (int j = 0; j < 4; ++j) s[j] += dA[j][k] * w;
      }
#pragma unroll
      for (int j = 0; j < 4; ++j) dB[j][tid] = s[j] > 0.0 ? s[j] : 0.2 * s[j];
      __syncthreads();
    }
    {
      double w2 = (double)tw2[tid];
#pragma unroll
      for (int j = 0; j < 4; ++j) dA[j][tid] = dB[j][tid] * w2;
      __syncthreads();
      for (int off = 64; off > 0; off >>= 1) {
        if (tid < off) {
#pragma unroll
          for (int j = 0; j < 4; ++j) dA[j][tid] += dA[j][tid + off];
        }
        __syncthreads();
      }
      if (tid == 0) {
#pragma unroll
        for (int j = 0; j < 4; ++j) {
          double tval = dA[j][0] + (double)tb2[0];
          double sg = 1.0 / (1.0 + exp(-tval));
          float tf = (float)sg;            // round like the fp32 reference
          timev[rg * 4 + j] = tf * 1.0f + times[rg * 4 + j];
        }
      }
    }
  } else if (stack == 1) {
    // ---- amp stack, fp32 ----
    {
      float b = ab0[tid];
      float s[4] = {b, b, b, b};
#pragma unroll 8
      for (int k = 0; k < MD; ++k) {
        float w = aw0[k * MD + tid];
#pragma unroll
        for (int j = 0; j < 4; ++j) s[j] += xs[j][k] * w;
      }
#pragma unroll
      for (int j = 0; j < 4; ++j) fA[j][tid] = lrelu(s[j]);
      __syncthreads();
    }
    {
      float b = ab1[tid];
      float s[4] = {b, b, b, b};
#pragma unroll 8
      for (int k = 0; k < MD; ++k) {
        float w = aw1[k * MD + tid];
#pragma unroll
        for (int j = 0; j < 4; ++j) s[j] += fA[j][k] * w;
      }
#pragma unroll
      for (int j = 0; j < 4; ++j) fB[j][tid] = lrelu(s[j]);
      __syncthreads();
    }
    {
      float w2 = aw2[tid];
#pragma unroll
      for (int j = 0; j < 4; ++j) fA[j][tid] = fB[j][tid] * w2;
      __syncthreads();
      for (int off = 64; off > 0; off >>= 1) {
        if (tid < off) {
#pragma unroll
          for (int j = 0; j < 4; ++j) fA[j][tid] += fA[j][tid + off];
        }
        __syncthreads();
      }
      if (tid == 0) {
#pragma unroll
        for (int j = 0; j < 4; ++j) {
          float av = fA[j][0] + ab2[0];
          ampv[rg * 4 + j] = av * av;
        }
      }
    }
  } else {
    // ---- selection hidden, fp32 ----
    {
      float b = sb0[tid];
      float s[4] = {b, b, b, b};
#pragma unroll 8
      for (int k = 0; k < MD; ++k) {
        float w = sw0[k * MD + tid];
#pragma unroll
        for (int j = 0; j < 4; ++j) s[j] += xs[j][k] * w;
      }
#pragma unroll
      for (int j = 0; j < 4; ++j) fA[j][tid] = lrelu(s[j]);
      __syncthreads();
    }
    {
      float b = sb1[tid];
      float s[4] = {b, b, b, b};
#pragma unroll 8
      for (int k = 0; k < MD; ++k) {
        float w = sw1[k * MD + tid];
#pragma unroll
        for (int j = 0; j < 4; ++j) s[j] += fA[j][k] * w;
      }
#pragma unroll
      for (int j = 0; j < 4; ++j)
        h2sel[(rg * 4 + j) * MD + tid] = lrelu(s[j]);
    }
  }
}

// ---------------------------------------------------------------------------
// P2: selection logits + gumbel + per-tile argmax partials.
// Grid (16 o-tiles, 128 be-groups) x 128.
// ---------------------------------------------------------------------------
__global__ __launch_bounds__(128) void logits_kernel(
    const float* __restrict__ h2sel, const float* __restrict__ gu,
    const float* __restrict__ sw2, const float* __restrict__ sb2,
    float2* __restrict__ partials)
{
  const int ot = blockIdx.x;     // 0..15
  const int beg = blockIdx.y;    // 0..127
  const int tid = threadIdx.x;
  const int o = ot * 128 + tid;
  const int wave = tid >> 6, lane = tid & 63;

  __shared__ float h2s[4][MD];
  __shared__ float wv[2][4];
  __shared__ int wi[2][4];

#pragma unroll
  for (int j = 0; j < 4; ++j) h2s[j][tid] = h2sel[(beg * 4 + j) * MD + tid];
  __syncthreads();

  float b = sb2[o];
  float acc[4] = {b, b, b, b};
#pragma unroll 16
  for (int k = 0; k < MD; ++k) {
    float w = sw2[k * NA + o];
#pragma unroll
    for (int j = 0; j < 4; ++j) acc[j] = fmaf(h2s[j][k], w, acc[j]);
  }

#pragma unroll
  for (int j = 0; j < 4; ++j) {
    float u = gu[(beg * 4 + j) * NA + o];
    float g = -logf(-logf(u + 1e-10f) + 1e-10f);
    float v = acc[j] + g;
    int idx = o;
    for (int off = 32; off > 0; off >>= 1) {
      float ov = __shfl_xor(v, off);
      int oi = __shfl_xor(idx, off);
      if (ov > v || (ov == v && oi < idx)) { v = ov; idx = oi; }
    }
    if (lane == 0) { wv[wave][j] = v; wi[wave][j] = idx; }
  }
  __syncthreads();
  if (tid == 0) {
#pragma unroll
    for (int j = 0; j < 4; ++j) {
      float v0 = wv[0][j], v1 = wv[1][j];
      int i0 = wi[0][j], i1 = wi[1][j];
      bool take1 = (v1 > v0) || (v1 == v0 && i1 < i0);
      float bv = take1 ? v1 : v0;
      int bi = take1 ? i1 : i0;
      partials[(beg * 4 + j) * 16 + ot] = make_float2(bv, __int_as_float(bi));
    }
  }
}

// ---------------------------------------------------------------------------
// P3: final argmax + atom norm + shift params + G/moments(0..8)/params,
// plus compacted work-item append (be's whose near window intersects [0,NS)).
// params[be][3]: {uc, lo, hi, M0}, {M1..M4}, {M5..M8}.
// ---------------------------------------------------------------------------
__global__ __launch_bounds__(128) void finalize_kernel(
    const float2* __restrict__ partials, const float* __restrict__ timev,
    const float* __restrict__ ampv, const float* __restrict__ atoms,
    float* __restrict__ G, int* __restrict__ m0s, float* __restrict__ fracs,
    float4* __restrict__ params, int* __restrict__ counter,
    int* __restrict__ items)
{
  const int be = blockIdx.x;
  const int tid = threadIdx.x;
  __shared__ float red[128];
  __shared__ float m_red[128][9];
  __shared__ float sc_coef, sc_inv;
  __shared__ int sc_idx;

  if (tid < 64) {
    float v = -3.4e38f;
    int idx = 0x7fffffff;
    if (tid < 16) {
      float2 p = partials[be * 16 + tid];
      v = p.x;
      idx = __float_as_int(p.y);
    }
    for (int off = 8; off > 0; off >>= 1) {
      float ov = __shfl_xor(v, off);
      int oi = __shfl_xor(idx, off);
      if (ov > v || (ov == v && oi < idx)) { v = ov; idx = oi; }
    }
    if (tid == 0) sc_idx = idx;
  }
  __syncthreads();
  const int idx = sc_idx;

  {
    float ss = 0.f;
    for (int i = tid; i < AS; i += 128) { float v = atoms[idx * AS + i]; ss += v * v; }
    red[tid] = ss;
    __syncthreads();
    for (int off = 64; off > 0; off >>= 1) {
      if (tid < off) red[tid] += red[tid + off];
      __syncthreads();
    }
    if (tid == 0) {
      sc_inv = 1.f / (sqrtf(red[0]) + 1e-8f);
      double Nc = (double)timev[be] * (1610612736.0 / 49153.0);
      double rr = rint(Nc);
      int m0 = (int)rr;
      float fr = (float)(Nc - rr);
      if (fabsf(fr) < 1e-9f) fr = (fr < 0.f) ? -1e-9f : 1e-9f;
      m0s[be] = m0;
      fracs[be] = fr;
      sc_coef = ampv[be] * ((m0 & 1) ? 1.0f : -1.0f) *
                sinf((float)PI * fr) * (1.0f / 98304.0f);
      red[64] = (float)m0;
      red[65] = fr;
      if (m0 - W1 < NS) {                 // near window intersects output
        int pos = atomicAdd(counter, 1);
        items[pos] = be;
      }
    }
    __syncthreads();
  }

  const float cf = sc_coef * sc_inv;
  float mk[9] = {0.f, 0.f, 0.f, 0.f, 0.f, 0.f, 0.f, 0.f, 0.f};
  for (int t = tid; t < AS; t += 128) {
    float av = atoms[idx * AS + t] * cf;
    float gv = (t & 1) ? -av : av;
    G[be * AS + t] = gv;
    float q = (255.5f - (float)t) * KTH;
    float pw = gv;
    mk[0] += pw;
#pragma unroll
    for (int k = 1; k < 9; ++k) { pw *= q; mk[k] += pw; }
  }
#pragma unroll
  for (int k = 0; k < 9; ++k) m_red[tid][k] = mk[k];
  __syncthreads();
  for (int off = 64; off > 0; off >>= 1) {
    if (tid < off) {
#pragma unroll
      for (int k = 0; k < 9; ++k) m_red[tid][k] += m_red[tid + off][k];
    }
    __syncthreads();
  }
  if (tid == 0) {
    int m0 = (int)red[64];
    float fr = red[65];
    float uc = (float)((double)m0 + (double)fr + 255.5);
    params[be * 3 + 0] = make_float4(uc, (float)(m0 - W1), (float)(m0 + W2), m_red[0][0]);
    params[be * 3 + 1] = make_float4(m_red[0][1], m_red[0][2], m_red[0][3], m_red[0][4]);
    params[be * 3 + 2] = make_float4(m_red[0][5], m_red[0][6], m_red[0][7], m_red[0][8]);
  }
}

// ---------------------------------------------------------------------------
// Fused field kernel. Blocks [0,1024): far (P=8 Taylor, atomicAdd onto
// zeroed out). Blocks [1024,1024+count): near (one 2048-window per active be,
// round-7 split-table conv, proven conflict-free pattern). Co-scheduling the
// two phases hides near's low wave count under far's 4096 waves.
// ---------------------------------------------------------------------------
__global__ __launch_bounds__(256) void field_kernel(
    const float4* __restrict__ params, const float* __restrict__ G,
    const int* __restrict__ m0s, const float* __restrict__ fracs,
    const int* __restrict__ counter, const int* __restrict__ items,
    float* __restrict__ out)
{
  __shared__ float4 SMEM[768];   // far: Pl[192] | near: Tsplit[640] + Gl4[128]
  const int bid = blockIdx.x;
  const int tid = threadIdx.x;

  if (bid < 1024) {
    // ================= far path =================
    float4* Pl = SMEM;
    const int b = bid >> 7;
    const int t = (bid & 127) * 256 + tid;
    if (tid < 192) Pl[tid] = params[b * 192 + tid];
    __syncthreads();

    const float tf = (float)t;
    float acc = 0.f;
#pragma unroll 2
    for (int e = 0; e < 64; ++e) {
      const float4 A = Pl[e * 3 + 0];
      const float4 B = Pl[e * 3 + 1];
      const float4 C = Pl[e * 3 + 2];
      float u  = tf - A.x;
      float th = u * KTH;
      float sn = __sinf(th);
      float cs = __cosf(th);
      float c  = cs * __builtin_amdgcn_rcpf(sn);
      float u2  = __builtin_fmaf(c, c, 1.f);     // -a1
      float c2  = c + c;
      float u22 = u2 + u2;
      float a2  = c * u2;
      float a3  = (-1.f / 3.f) * __builtin_fmaf(c2, a2, u2 * u2);
      float a4  = 0.5f * __builtin_fmaf(-c, a3, u2 * a2);
      float s5  = __builtin_fmaf(c2, a4, a2 * a2);
      s5        = __builtin_fmaf(-u22, a3, s5);
      float a5  = -0.2f * s5;
      float s6  = __builtin_fmaf(c, a5, a2 * a3);
      s6        = __builtin_fmaf(-u2, a4, s6);
      float a6  = (-1.f / 3.f) * s6;
      float s7  = __builtin_fmaf(c2, a6, a3 * a3);
      s7        = __builtin_fmaf(-u22, a5, s7);
      s7        = __builtin_fmaf(2.f * a2, a4, s7);
      float a7  = (-1.f / 7.f) * s7;
      float s8  = __builtin_fmaf(c, a7, a3 * a4);
      s8        = __builtin_fmaf(-u2, a6, s8);
      s8        = __builtin_fmaf(a2, a5, s8);
      float a8  = -0.25f * s8;
      float y = c * A.w;
      y = __builtin_fmaf(-u2, B.x, y);
      y = __builtin_fmaf(a2, B.y, y);
      y = __builtin_fmaf(a3, B.z, y);
      y = __builtin_fmaf(a4, B.w, y);
      y = __builtin_fmaf(a5, C.x, y);
      y = __builtin_fmaf(a6, C.y, y);
      y = __builtin_fmaf(a7, C.z, y);
      y = __builtin_fmaf(a8, C.w, y);
      bool farq = (tf < A.y) || (tf >= A.z);
      acc += farq ? y : 0.f;
    }
    atomicAdd(&out[b * NS + t], (t & 1) ? -acc : acc);
    return;
  }

  // ================= near path =================
  const int j = bid - 1024;
  if (j >= counter[0]) return;   // block-uniform
  const int be = items[j];
  const int m0 = m0s[be];
  const int start = m0 - W1;
  const float fr = fracs[be];
  const int b = be >> 6;

  float4* Tsplit = SMEM;         // [0..319]=even groups, [320..639]=odd
  float*  Tf = (float*)Tsplit;
  float*  Gl = (float*)(SMEM + 640);
  const float4* Gl4 = SMEM + 640;

  for (int i = tid; i < AS; i += 256) Gl[i] = G[be * AS + i];
  for (int i = tid; i < 2560; i += 256) {
    int v = start - 511 + i;
    float w = (float)(v - m0) - fr;           // never 0 (|fr| >= 1e-9)
    float th = w * KTH;                       // |th| <= 0.041
    float q = th * th;
    float sn = th * __builtin_fmaf(q, __builtin_fmaf(q, (1.f / 120.f), (-1.f / 6.f)), 1.f);
    float cs = __builtin_fmaf(q, __builtin_fmaf(q, (1.f / 24.f), -0.5f), 1.f);
    float val = cs * __builtin_amdgcn_rcpf(sn);
    int g = i >> 2;                           // logical float4 group
    int s = (g >> 1) * 4 + (i & 3) + (g & 1) * 1280;  // split index (floats)
    Tf[s] = val;
  }
  __syncthreads();

  float acc[8];
#pragma unroll
  for (int r = 0; r < 8; ++r) acc[r] = 0.f;

  float Wf[16];
  {
    float4 qa = Tsplit[tid];         // group 2*tid   -> Wf[0..3]
    float4 qb = Tsplit[320 + tid];   // group 2*tid+1 -> Wf[4..7]
    Wf[0] = qa.x; Wf[1] = qa.y; Wf[2] = qa.z; Wf[3] = qa.w;
    Wf[4] = qb.x; Wf[5] = qb.y; Wf[6] = qb.z; Wf[7] = qb.w;
  }
#pragma unroll 4
  for (int k = 0; k < 64; ++k) {
    float4 qa = Tsplit[tid + k + 1];         // group 2(tid+k+1)
    float4 qb = Tsplit[320 + tid + k + 1];   // group 2(tid+k+1)+1
    Wf[8]  = qa.x; Wf[9]  = qa.y; Wf[10] = qa.z; Wf[11] = qa.w;
    Wf[12] = qb.x; Wf[13] = qb.y; Wf[14] = qb.z; Wf[15] = qb.w;
    const int tc = 504 - 8 * k;
    const float4 gq0 = Gl4[tc >> 2];
    const float4 gq1 = Gl4[(tc >> 2) + 1];
    const float gvals[8] = {gq0.x, gq0.y, gq0.z, gq0.w,
                            gq1.x, gq1.y, gq1.z, gq1.w};
#pragma unroll
    for (int d = 0; d < 8; ++d) {
      const float gv = gvals[d];
#pragma unroll
      for (int r = 0; r < 8; ++r)
        acc[r] = fmaf(gv, Wf[7 + r - d], acc[r]);
    }
#pragma unroll
    for (int m = 0; m < 8; ++m) Wf[m] = Wf[m + 8];
  }

  const int tb = start + tid * 8;
#pragma unroll
  for (int r = 0; r < 8; ++r) {
    int t = tb + r;
    if (t >= 0 && t < NS) {
      float v = (t & 1) ? -acc[r] : acc[r];
      atomicAdd(&out[b * NS + t], v);
    }
  }
}

// ---------------------------------------------------------------------------
extern "C" void kernel_launch(void* const* d_in, const int* in_sizes, int n_in,
                              void* d_out, int out_size, void* d_ws, size_t ws_size,
                              hipStream_t stream) {
  const float* x     = (const float*)d_in[0];
  const float* times = (const float*)d_in[1];
  const float* gu    = (const float*)d_in[2];
  const float* atoms = (const float*)d_in[3];
  const float* tw0 = (const float*)d_in[4];  const float* tb0 = (const float*)d_in[5];
  const float* tw1 = (const float*)d_in[6];  const float* tb1 = (const float*)d_in[7];
  const float* tw2 = (const float*)d_in[8];  const float* tb2 = (const float*)d_in[9];
  const float* sw0 = (const float*)d_in[10]; const float* sb0 = (const float*)d_in[11];
  const float* sw1 = (const float*)d_in[12]; const float* sb1 = (const float*)d_in[13];
  const float* sw2 = (const float*)d_in[14]; const float* sb2 = (const float*)d_in[15];
  const float* aw0 = (const float*)d_in[16]; const float* ab0 = (const float*)d_in[17];
  const float* aw1 = (const float*)d_in[18]; const float* ab1 = (const float*)d_in[19];
  const float* aw2 = (const float*)d_in[20]; const float* ab2 = (const float*)d_in[21];

  // ws layout (bytes):
  //   G 0..1MB | m0s 1048576 | fracs 1050624 | params 1052672 (24KB)
  //   timev 1077248 | ampv 1079296 | h2sel 1081344 (256KB)
  //   partials 1343488 (64KB) | counter 1409024 | items 1409028 (2KB)
  char* wsb = (char*)d_ws;
  float*  G        = (float*)wsb;
  int*    m0s      = (int*)(wsb + 1048576);
  float*  fracs    = (float*)(wsb + 1050624);
  float4* params   = (float4*)(wsb + 1052672);
  float*  timev    = (float*)(wsb + 1077248);
  float*  ampv     = (float*)(wsb + 1079296);
  float*  h2sel    = (float*)(wsb + 1081344);
  float2* partials = (float2*)(wsb + 1343488);
  int*    counter  = (int*)(wsb + 1409024);
  int*    items    = (int*)(wsb + 1409028);

  hipMemsetAsync(counter, 0, 4, stream);
  hipMemsetAsync(d_out, 0, (size_t)out_size * sizeof(float), stream);

  hidden_kernel<<<dim3(NBE / 4, 3), 128, 0, stream>>>(
      x, times, tw0, tb0, tw1, tb1, tw2, tb2,
      sw0, sb0, sw1, sb1, aw0, ab0, aw1, ab1, aw2, ab2,
      timev, ampv, h2sel);

  logits_kernel<<<dim3(16, NBE / 4), 128, 0, stream>>>(h2sel, gu, sw2, sb2, partials);

  finalize_kernel<<<NBE, 128, 0, stream>>>(partials, timev, ampv, atoms,
                                           G, m0s, fracs, params, counter, items);

  field_kernel<<<1024 + NBE, 256, 0, stream>>>(params, G, m0s, fracs,
                                               counter, items, (float*)d_out);
}